// Round 3
// baseline (115.566 us; speedup 1.0000x reference)
//
#include <hip/hip_runtime.h>
#include <stdint.h>

// CausalDerivative: out[b,i] = sum_h W2[i,h] * relu(sum_n x[b,n]*W1[i,h,n]*M[i,n])
//   x[b,n] = (n<16) ? (inputs[b,n]>0 ? 1 : 0) : inputs[b,n]
//   M = ones, except row 63 keeps only n==63
// B=32768, N=64, H=64. Device tensors FP32 (proven r3/6/7); dual-path kept.
//
// Round 15: second resubmit of the node-split kernel (rounds 13/14 died to
// "container failed twice" with no compile/test verdict; audit found no OOB
// or hang candidate). Delta vs r14: main_kernel back to launch_bounds(256,2)
// (the r12-proven flag). VGPR=100 rounds to the 128 granule, so hardware
// residency is 4 blocks/CU regardless of the hint; the occupancy lever is
// grid 1024 (64 rows x 32 nodes per block, 8 nodes/wave), not the bound.

typedef __attribute__((ext_vector_type(8))) short short8;   // 8 bf16
typedef __attribute__((ext_vector_type(4))) float floatx4;  // MFMA acc

#define NN 64
#define HH 64
#define BB 32768
#define OTW 33    // out-tile row stride in floats (odd -> conflict-benign)
#define X_ELEMS (BB * NN)        // 2097152
#define W1_ELEMS (NN * HH * NN)  // 262144

__device__ __forceinline__ unsigned short f32_to_bf16_bits(float f) {
    union { float f; unsigned int i; } c; c.f = f;
    unsigned int b = c.i;
    b += 0x7fffu + ((b >> 16) & 1u);   // RNE
    return (unsigned short)(b >> 16);
}

__device__ __forceinline__ bool sniff_bf16(const void* x) {
    // bf16 N(0,1): exponent field in [118,132] ~99%; fp32 low-mantissa halves ~6%.
    const int lane = threadIdx.x & 63;
    const ushort* xw = (const ushort*)x;
    const ushort a = xw[4 * lane];
    const ushort b = xw[4 * lane + 2];
    const int ea = (a >> 7) & 0xFF, eb = (b >> 7) & 0xFF;
    const int hit = ((ea >= 118 && ea <= 132) ? 1 : 0) + ((eb >= 118 && eb <= 132) ? 1 : 0);
    const unsigned long long m1 = __ballot(hit >= 1);
    const unsigned long long m2 = __ballot(hit >= 2);
    return (__popcll(m1) + __popcll(m2)) >= 64;
}

// ---------------- prep: gate+convert x, mask+convert W1 into bf16 workspace ----
__global__ __launch_bounds__(256, 4)
void prep_kernel(const void* __restrict__ x, const void* __restrict__ w1,
                 ushort* __restrict__ xo, ushort* __restrict__ w1o)
{
    const bool is_bf16 = sniff_bf16(x);
    const long base = ((long)blockIdx.x * 256 + (long)threadIdx.x) * 8;

    if (base < X_ELEMS) {
        const bool gate = (base & 63) < 16;   // uniform per 8-elem chunk
        short8 v;
        if (is_bf16) {
            v = *(const short8*)((const ushort*)x + base);
            if (gate) {
                #pragma unroll
                for (int j = 0; j < 8; ++j) {
                    const unsigned short u = (unsigned short)v[j];
                    const bool pos = ((u & 0x8000u) == 0) && ((u & 0x7fffu) != 0);
                    v[j] = pos ? (short)0x3F80 : (short)0;
                }
            }
        } else {
            const float* p = (const float*)x + base;
            const float4 f0 = *(const float4*)(p);
            const float4 f1 = *(const float4*)(p + 4);
            const float vals[8] = {f0.x, f0.y, f0.z, f0.w, f1.x, f1.y, f1.z, f1.w};
            #pragma unroll
            for (int j = 0; j < 8; ++j) {
                if (gate) v[j] = (vals[j] > 0.f) ? (short)0x3F80 : (short)0;
                else      v[j] = (short)f32_to_bf16_bits(vals[j]);
            }
        }
        *(short8*)(xo + base) = v;
    } else {
        const long wb = base - X_ELEMS;
        if (wb < W1_ELEMS) {
            short8 v;
            if (is_bf16) {
                v = *(const short8*)((const ushort*)w1 + wb);
            } else {
                const float* p = (const float*)w1 + wb;
                const float4 f0 = *(const float4*)(p);
                const float4 f1 = *(const float4*)(p + 4);
                const float vals[8] = {f0.x, f0.y, f0.z, f0.w, f1.x, f1.y, f1.z, f1.w};
                #pragma unroll
                for (int j = 0; j < 8; ++j) v[j] = (short)f32_to_bf16_bits(vals[j]);
            }
            const int node = (int)(wb >> 12);        // 4096 elems per node
            if (node == NN - 1) {                    // hidden node: keep only n==63
                const int w63 = (int)(wb & 63);
                #pragma unroll
                for (int j = 0; j < 8; ++j)
                    if (w63 + j != NN - 1) v[j] = 0;
            }
            *(short8*)(w1o + wb) = v;
        }
    }
}

// ---------------- main: 64 rows x 32 nodes per block, 8 nodes/wave ------------
template<bool F32>
__device__ __forceinline__ void main_body(const ushort* __restrict__ xo,
                                          const ushort* __restrict__ w1o,
                                          const void* __restrict__ w2p,
                                          void* __restrict__ outp,
                                          float* outTile)
{
    const int tid  = threadIdx.x;
    const int wave = tid >> 6;
    const int lane = tid & 63;
    const int quad = lane >> 4;   // 0..3
    const int l16  = lane & 15;   // 0..15

    const int blk   = blockIdx.x;        // 0..1023
    const int b0    = (blk >> 1) * 64;   // this block's 64 batch rows
    const int nhalf = blk & 1;           // which 32-node half
    const int nbase = nhalf * 32 + wave * 8;  // this wave's 8 nodes (global ids)

    // ---- x fragments, loaded ONCE, reused by 8 node-GEMMs. Role: MFMA *B*
    //      B[k][bcol] = xo[b0+bcol][k]; bcol = nt*16+l16, k = ks*32+quad*8+j
    short8 xfrag[2][4];
    #pragma unroll
    for (int ks = 0; ks < 2; ++ks)
        #pragma unroll
        for (int nt = 0; nt < 4; ++nt)
            xfrag[ks][nt] = *(const short8*)(xo + (b0 + nt * 16 + l16) * NN + ks * 32 + quad * 8);

    // ---- W1 fragment loader (role: MFMA *A*): A[h][k] = W1[node][h][k]
    auto loadW1 = [&](short8 w[2][4], int node) {
        const ushort* w1n = w1o + node * (HH * NN);
        #pragma unroll
        for (int ks = 0; ks < 2; ++ks)
            #pragma unroll
            for (int mt = 0; mt < 4; ++mt)
                w[ks][mt] = *(const short8*)(w1n + (mt * 16 + l16) * NN + ks * 32 + quad * 8);
    };

    // ---- one node's GEMM + in-lane epilogue (r11-proven layout)
    auto computeNode = [&](const short8 w[2][4], int node) {
        // W2 loads issued first; needed only after the 32 MFMAs -> latency hidden
        float w2v[4][4];
        #pragma unroll
        for (int mt = 0; mt < 4; ++mt) {
            const int idx = node * HH + mt * 16 + quad * 4;
            if (F32) {
                const float4 ww = *(const float4*)((const float*)w2p + idx);
                w2v[mt][0] = ww.x; w2v[mt][1] = ww.y; w2v[mt][2] = ww.z; w2v[mt][3] = ww.w;
            } else {
                const ushort4 ww = *(const ushort4*)((const ushort*)w2p + idx);
                union { unsigned int i; float f; } c0, c1, c2, c3;
                c0.i = ((unsigned int)ww.x) << 16; c1.i = ((unsigned int)ww.y) << 16;
                c2.i = ((unsigned int)ww.z) << 16; c3.i = ((unsigned int)ww.w) << 16;
                w2v[mt][0] = c0.f; w2v[mt][1] = c1.f; w2v[mt][2] = c2.f; w2v[mt][3] = c3.f;
            }
        }

        // MFMA (transposed): acc[mt][nt] = Hid^T tile; D row = h offset
        // (quad*4+r within mt), D col = batch (l16 within nt).
        floatx4 acc[4][4];
        #pragma unroll
        for (int mt = 0; mt < 4; ++mt)
            #pragma unroll
            for (int nt = 0; nt < 4; ++nt)
                acc[mt][nt] = (floatx4){0.f, 0.f, 0.f, 0.f};

        #pragma unroll
        for (int ks = 0; ks < 2; ++ks)
            #pragma unroll
            for (int mt = 0; mt < 4; ++mt)
                #pragma unroll
                for (int nt = 0; nt < 4; ++nt)
                    acc[mt][nt] = __builtin_amdgcn_mfma_f32_16x16x32_bf16(
                        w[ks][mt], xfrag[ks][nt], acc[mt][nt], 0, 0, 0);

        // in-lane: psum[nt] = sum over this lane's 16 h-values
        float psum[4];
        #pragma unroll
        for (int nt = 0; nt < 4; ++nt) {
            float s0 = 0.f, s1 = 0.f;
            #pragma unroll
            for (int mt = 0; mt < 4; ++mt) {
                float a0 = acc[mt][nt][0]; a0 = a0 > 0.f ? a0 : 0.f;
                float a1 = acc[mt][nt][1]; a1 = a1 > 0.f ? a1 : 0.f;
                float a2 = acc[mt][nt][2]; a2 = a2 > 0.f ? a2 : 0.f;
                float a3 = acc[mt][nt][3]; a3 = a3 > 0.f ? a3 : 0.f;
                s0 = fmaf(a0, w2v[mt][0], s0); s1 = fmaf(a1, w2v[mt][1], s1);
                s0 = fmaf(a2, w2v[mt][2], s0); s1 = fmaf(a3, w2v[mt][3], s1);
            }
            psum[nt] = s0 + s1;
        }

        // reduce across the 4 quads (same batch col, different h ranges)
        #pragma unroll
        for (int nt = 0; nt < 4; ++nt) {
            psum[nt] += __shfl_xor(psum[nt], 16, 64);
            psum[nt] += __shfl_xor(psum[nt], 32, 64);
        }

        // lane's batch row == lane (nt = quad, col = l16): select psum[quad]
        const float val = (quad == 0) ? psum[0] : (quad == 1) ? psum[1]
                         : (quad == 2) ? psum[2] : psum[3];
        outTile[lane * OTW + (node & 31)] = val;   // lane-major: 2-way aliasing only
    };

    // ---- 8-node loop, ping-pong double buffer (no register rotation)
    short8 wA[2][4], wB[2][4];
    loadW1(wA, nbase);
    #pragma unroll 1
    for (int np = 0; np < 8; np += 2) {
        loadW1(wB, nbase + np + 1);          // np+1 <= 7 always
        computeNode(wA, nbase + np);
        if (np + 2 < 8) loadW1(wA, nbase + np + 2);
        computeNode(wB, nbase + np + 1);
    }

    __syncthreads();   // all 32 out-tile columns written

    // ---- output: thread -> (row = tid>>2, eighth q = tid&3); each thread
    // writes 32B contiguous: out[b0+row][nhalf*32 + q*8 .. +7]
    const int row = tid >> 2;
    const int q   = tid & 3;
    const float* rp = outTile + row * OTW + q * 8;
    const size_t obase = (size_t)(b0 + row) * NN + nhalf * 32 + q * 8;
    if (F32) {
        float* op = (float*)outp + obase;
        *(float4*)(op)     = make_float4(rp[0], rp[1], rp[2], rp[3]);
        *(float4*)(op + 4) = make_float4(rp[4], rp[5], rp[6], rp[7]);
    } else {
        ushort* op = (ushort*)outp + obase;
        short8 o;
        #pragma unroll
        for (int c = 0; c < 8; ++c) o[c] = (short)f32_to_bf16_bits(rp[c]);
        *(short8*)(op) = o;
    }
}

__global__ __launch_bounds__(256, 2)
void main_kernel(const void* __restrict__ xorig,
                 const ushort* __restrict__ xo, const ushort* __restrict__ w1o,
                 const void* __restrict__ w2p, void* __restrict__ outp)
{
    __shared__ float outTile[64 * OTW];   // 8.25 KB
    const bool is_bf16 = sniff_bf16(xorig);
    if (is_bf16) main_body<false>(xo, w1o, w2p, outp, outTile);
    else         main_body<true >(xo, w1o, w2p, outp, outTile);
}

// ---------------- fallback: round-6 proven single kernel ----------------------
#define LDSW 20
template<bool F32>
__device__ __forceinline__ void run_body_fb(const void* xp, const void* w1p,
                                            const void* w2p, void* outp,
                                            float* myLds)
{
    const int tid  = threadIdx.x;
    const int wave = tid >> 6;
    const int lane = tid & 63;
    const int quad = lane >> 4;
    const int l16  = lane & 15;
    const int blk  = blockIdx.x;
    const int ng   = blk >> 7;
    const int rbg  = blk & 127;
    const int node = ng * 4 + wave;
    const int rowbase = rbg * 256;

    short8 bfrag[2][4];
    #pragma unroll
    for (int ks = 0; ks < 2; ++ks) {
        #pragma unroll
        for (int ht = 0; ht < 4; ++ht) {
            const int h = ht * 16 + l16;
            const int k = ks * 32 + quad * 8;
            short8 v;
            if (F32) {
                const float* p = (const float*)w1p + node * (HH * NN) + h * NN + k;
                const float4 a0 = *(const float4*)(p);
                const float4 a1 = *(const float4*)(p + 4);
                const float vals[8] = {a0.x, a0.y, a0.z, a0.w, a1.x, a1.y, a1.z, a1.w};
                #pragma unroll
                for (int j = 0; j < 8; ++j) v[j] = (short)f32_to_bf16_bits(vals[j]);
            } else {
                v = *(const short8*)((const ushort*)w1p + node * (HH * NN) + h * NN + k);
            }
            if (node == NN - 1) {
                #pragma unroll
                for (int j = 0; j < 8; ++j)
                    if (k + j != NN - 1) v[j] = 0;
            }
            bfrag[ks][ht] = v;
        }
    }

    float w2reg[4];
    #pragma unroll
    for (int ht = 0; ht < 4; ++ht) {
        const int idx = node * HH + ht * 16 + l16;
        if (F32) {
            w2reg[ht] = ((const float*)w2p)[idx];
        } else {
            const ushort u = ((const ushort*)w2p)[idx];
            union { unsigned int i; float f; } cv; cv.i = ((unsigned int)u) << 16;
            w2reg[ht] = cv.f;
        }
    }

    #pragma unroll 1
    for (int it = 0; it < 4; ++it) {
        const int b0 = rowbase + it * 64;
        short8 afrag[2][4];
        #pragma unroll
        for (int ks = 0; ks < 2; ++ks) {
            #pragma unroll
            for (int rt = 0; rt < 4; ++rt) {
                const int rowg = b0 + rt * 16 + l16;
                const int k    = ks * 32 + quad * 8;
                const bool gate = (ks == 0 && quad < 2);
                short8 v;
                if (F32) {
                    const float* p = (const float*)xp + rowg * NN + k;
                    const float4 a0 = *(const float4*)(p);
                    const float4 a1 = *(const float4*)(p + 4);
                    const float vals[8] = {a0.x, a0.y, a0.z, a0.w, a1.x, a1.y, a1.z, a1.w};
                    #pragma unroll
                    for (int j = 0; j < 8; ++j) {
                        if (gate) v[j] = (vals[j] > 0.f) ? (short)0x3F80 : (short)0;
                        else      v[j] = (short)f32_to_bf16_bits(vals[j]);
                    }
                } else {
                    v = *(const short8*)((const ushort*)xp + rowg * NN + k);
                    if (gate) {
                        #pragma unroll
                        for (int j = 0; j < 8; ++j) {
                            const unsigned short u = (unsigned short)v[j];
                            const bool pos = ((u & 0x8000u) == 0) && ((u & 0x7fffu) != 0);
                            v[j] = pos ? (short)0x3F80 : (short)0;
                        }
                    }
                }
                afrag[ks][rt] = v;
            }
        }

        floatx4 acc[4][4];
        #pragma unroll
        for (int rt = 0; rt < 4; ++rt)
            #pragma unroll
            for (int ht = 0; ht < 4; ++ht)
                acc[rt][ht] = (floatx4){0.f, 0.f, 0.f, 0.f};
        #pragma unroll
        for (int ks = 0; ks < 2; ++ks)
            #pragma unroll
            for (int rt = 0; rt < 4; ++rt)
                #pragma unroll
                for (int ht = 0; ht < 4; ++ht)
                    acc[rt][ht] = __builtin_amdgcn_mfma_f32_16x16x32_bf16(
                        afrag[ks][rt], bfrag[ks][ht], acc[rt][ht], 0, 0, 0);

        #pragma unroll
        for (int rt = 0; rt < 4; ++rt) {
            #pragma unroll
            for (int r = 0; r < 4; ++r) {
                float s = 0.f;
                #pragma unroll
                for (int ht = 0; ht < 4; ++ht) {
                    float v = acc[rt][ht][r];
                    v = v > 0.f ? v : 0.f;
                    s = fmaf(v, w2reg[ht], s);
                }
                myLds[(rt * 16 + quad * 4 + r) * LDSW + l16] = s;
            }
        }
        __syncthreads();
        const float* rowp = myLds + lane * LDSW;
        const float4 v0 = *(const float4*)(rowp + 0);
        const float4 v1 = *(const float4*)(rowp + 4);
        const float4 v2 = *(const float4*)(rowp + 8);
        const float4 v3 = *(const float4*)(rowp + 12);
        const float tot = (((v0.x + v0.y) + (v0.z + v0.w)) + ((v1.x + v1.y) + (v1.z + v1.w)))
                        + (((v2.x + v2.y) + (v2.z + v2.w)) + ((v3.x + v3.y) + (v3.z + v3.w)));
        if (F32) ((float*) outp)[(size_t)(b0 + lane) * NN + node] = tot;
        else     ((ushort*)outp)[(size_t)(b0 + lane) * NN + node] = f32_to_bf16_bits(tot);
        __syncthreads();
    }
}

__global__ __launch_bounds__(256, 2)
void fallback_kernel(const void* __restrict__ x, const void* __restrict__ W1,
                     const void* __restrict__ W2, void* __restrict__ out)
{
    __shared__ float lds[4][64 * LDSW];
    const bool is_bf16 = sniff_bf16(x);
    float* myLds = &lds[threadIdx.x >> 6][0];
    if (is_bf16) run_body_fb<false>(x, W1, W2, out, myLds);
    else         run_body_fb<true >(x, W1, W2, out, myLds);
}

extern "C" void kernel_launch(void* const* d_in, const int* in_sizes, int n_in,
                              void* d_out, int out_size, void* d_ws, size_t ws_size,
                              hipStream_t stream) {
    // Resolve inputs by element count (robust to the scalar t being dropped):
    //   inputs = 2097152, W1 = 262144, W2 = first 4096 (adjacency is the other 4096).
    int i_in = -1, i_w1 = -1, i_w2 = -1;
    for (int i = 0; i < n_in; ++i) {
        const int s = in_sizes[i];
        if      (s == BB * NN  && i_in < 0) i_in = i;
        else if (s == NN*HH*NN && i_w1 < 0) i_w1 = i;
        else if (s == NN*HH    && i_w2 < 0) i_w2 = i;
    }
    if (i_in < 0) i_in = (n_in > 1) ? 1 : 0;
    if (i_w1 < 0) i_w1 = i_in + 1;
    if (i_w2 < 0) i_w2 = i_w1 + 1;

    const size_t need = (size_t)(X_ELEMS + W1_ELEMS) * sizeof(ushort);  // 4.5 MiB
    if (ws_size >= need) {
        ushort* xo  = (ushort*)d_ws;
        ushort* w1o = xo + X_ELEMS;
        prep_kernel<<<dim3((X_ELEMS + W1_ELEMS) / (256 * 8)), dim3(256), 0, stream>>>(
            d_in[i_in], d_in[i_w1], xo, w1o);
        main_kernel<<<dim3(1024), dim3(256), 0, stream>>>(
            d_in[i_in], xo, w1o, d_in[i_w2], d_out);
    } else {
        fallback_kernel<<<dim3(16 * 128), dim3(256), 0, stream>>>(
            d_in[i_in], d_in[i_w1], d_in[i_w2], d_out);
    }
}

// Round 4
// 113.807 us; speedup vs baseline: 1.0155x; 1.0155x over previous
//
#include <hip/hip_runtime.h>
#include <stdint.h>

// CausalDerivative: out[b,i] = sum_h W2[i,h] * relu(sum_n x[b,n]*W1[i,h,n]*M[i,n])
//   x[b,n] = (n<16) ? (inputs[b,n]>0 ? 1 : 0) : inputs[b,n]
//   M = ones, except row 63 keeps only n==63
// B=32768, N=64, H=64. Device tensors FP32 (proven r3/6/7); dual-path kept.
//
// Round 16: r15 post-mortem: grid 1024 did NOT raise occupancy (18%, dur
// still 50us). Cause: unified VGPR+AGPR allocation ~190 regs/thread
// (xfrag 32 + wA/wB 64 + acc[4][4] 64 + w2v 16 + misc) > 128 -> hard cap
// 2 waves/SIMD (gfx950 unified file; VGPR_Count=104 hides the AGPR side).
// Fix: per-mt epilogue interleave (acc[4][4] -> acc[4], -48 regs) and
// replace whole-node ping-pong with per-mt slice prefetch into the just-
// freed w[*][mt] regs (-64 regs). ~110 regs -> 4 waves/SIMD legal;
// launch_bounds(256,4) forces the allocator. Math identical (psum
// reassociated over h-blocks).

typedef __attribute__((ext_vector_type(8))) short short8;   // 8 bf16
typedef __attribute__((ext_vector_type(4))) float floatx4;  // MFMA acc

#define NN 64
#define HH 64
#define BB 32768
#define OTW 33    // out-tile row stride in floats (odd -> conflict-benign)
#define X_ELEMS (BB * NN)        // 2097152
#define W1_ELEMS (NN * HH * NN)  // 262144

__device__ __forceinline__ unsigned short f32_to_bf16_bits(float f) {
    union { float f; unsigned int i; } c; c.f = f;
    unsigned int b = c.i;
    b += 0x7fffu + ((b >> 16) & 1u);   // RNE
    return (unsigned short)(b >> 16);
}

__device__ __forceinline__ bool sniff_bf16(const void* x) {
    // bf16 N(0,1): exponent field in [118,132] ~99%; fp32 low-mantissa halves ~6%.
    const int lane = threadIdx.x & 63;
    const ushort* xw = (const ushort*)x;
    const ushort a = xw[4 * lane];
    const ushort b = xw[4 * lane + 2];
    const int ea = (a >> 7) & 0xFF, eb = (b >> 7) & 0xFF;
    const int hit = ((ea >= 118 && ea <= 132) ? 1 : 0) + ((eb >= 118 && eb <= 132) ? 1 : 0);
    const unsigned long long m1 = __ballot(hit >= 1);
    const unsigned long long m2 = __ballot(hit >= 2);
    return (__popcll(m1) + __popcll(m2)) >= 64;
}

// ---------------- prep: gate+convert x, mask+convert W1 into bf16 workspace ----
__global__ __launch_bounds__(256, 4)
void prep_kernel(const void* __restrict__ x, const void* __restrict__ w1,
                 ushort* __restrict__ xo, ushort* __restrict__ w1o)
{
    const bool is_bf16 = sniff_bf16(x);
    const long base = ((long)blockIdx.x * 256 + (long)threadIdx.x) * 8;

    if (base < X_ELEMS) {
        const bool gate = (base & 63) < 16;   // uniform per 8-elem chunk
        short8 v;
        if (is_bf16) {
            v = *(const short8*)((const ushort*)x + base);
            if (gate) {
                #pragma unroll
                for (int j = 0; j < 8; ++j) {
                    const unsigned short u = (unsigned short)v[j];
                    const bool pos = ((u & 0x8000u) == 0) && ((u & 0x7fffu) != 0);
                    v[j] = pos ? (short)0x3F80 : (short)0;
                }
            }
        } else {
            const float* p = (const float*)x + base;
            const float4 f0 = *(const float4*)(p);
            const float4 f1 = *(const float4*)(p + 4);
            const float vals[8] = {f0.x, f0.y, f0.z, f0.w, f1.x, f1.y, f1.z, f1.w};
            #pragma unroll
            for (int j = 0; j < 8; ++j) {
                if (gate) v[j] = (vals[j] > 0.f) ? (short)0x3F80 : (short)0;
                else      v[j] = (short)f32_to_bf16_bits(vals[j]);
            }
        }
        *(short8*)(xo + base) = v;
    } else {
        const long wb = base - X_ELEMS;
        if (wb < W1_ELEMS) {
            short8 v;
            if (is_bf16) {
                v = *(const short8*)((const ushort*)w1 + wb);
            } else {
                const float* p = (const float*)w1 + wb;
                const float4 f0 = *(const float4*)(p);
                const float4 f1 = *(const float4*)(p + 4);
                const float vals[8] = {f0.x, f0.y, f0.z, f0.w, f1.x, f1.y, f1.z, f1.w};
                #pragma unroll
                for (int j = 0; j < 8; ++j) v[j] = (short)f32_to_bf16_bits(vals[j]);
            }
            const int node = (int)(wb >> 12);        // 4096 elems per node
            if (node == NN - 1) {                    // hidden node: keep only n==63
                const int w63 = (int)(wb & 63);
                #pragma unroll
                for (int j = 0; j < 8; ++j)
                    if (w63 + j != NN - 1) v[j] = 0;
            }
            *(short8*)(w1o + wb) = v;
        }
    }
}

// ---------------- main: 64 rows x 32 nodes per block, 8 nodes/wave ------------
// Register-lean: acc[4] per mt-slice (not [4][4]); W1 single buffer with
// per-mt-slice prefetch of the next node into the just-consumed registers.
template<bool F32>
__device__ __forceinline__ void main_body(const ushort* __restrict__ xo,
                                          const ushort* __restrict__ w1o,
                                          const void* __restrict__ w2p,
                                          void* __restrict__ outp,
                                          float* outTile)
{
    const int tid  = threadIdx.x;
    const int wave = tid >> 6;
    const int lane = tid & 63;
    const int quad = lane >> 4;   // 0..3
    const int l16  = lane & 15;   // 0..15

    const int blk   = blockIdx.x;        // 0..1023
    const int b0    = (blk >> 1) * 64;   // this block's 64 batch rows
    const int nhalf = blk & 1;           // which 32-node half
    const int nbase = nhalf * 32 + wave * 8;  // this wave's 8 nodes (global ids)

    // ---- x fragments, loaded ONCE, reused by 8 node-GEMMs. Role: MFMA *B*
    //      B[k][bcol] = xo[b0+bcol][k]; bcol = nt*16+l16, k = ks*32+quad*8+j
    short8 xfrag[2][4];
    #pragma unroll
    for (int ks = 0; ks < 2; ++ks)
        #pragma unroll
        for (int nt = 0; nt < 4; ++nt)
            xfrag[ks][nt] = *(const short8*)(xo + (b0 + nt * 16 + l16) * NN + ks * 32 + quad * 8);

    // ---- W1 single buffer, one mt-slice (both ks) loadable at a time.
    //      Role: MFMA *A*: A[h][k] = W1[node][h][k], h = mt*16+l16.
    short8 w[2][4];
    auto loadW1mt = [&](int node, int mt) {
        const ushort* w1n = w1o + node * (HH * NN) + (mt * 16 + l16) * NN + quad * 8;
        w[0][mt] = *(const short8*)(w1n);
        w[1][mt] = *(const short8*)(w1n + 32);
    };

    // preload node 0's four slices
    #pragma unroll
    for (int mt = 0; mt < 4; ++mt) loadW1mt(nbase, mt);

    #pragma unroll 1
    for (int np = 0; np < 8; ++np) {
        const int node = nbase + np;
        const int nextnode = (np < 7) ? (node + 1) : node;  // clamp: in-bounds dummy

        // W2 for this node (16 regs, consumed per mt-epilogue)
        float w2v[4][4];
        #pragma unroll
        for (int mt = 0; mt < 4; ++mt) {
            const int idx = node * HH + mt * 16 + quad * 4;
            if (F32) {
                const float4 ww = *(const float4*)((const float*)w2p + idx);
                w2v[mt][0] = ww.x; w2v[mt][1] = ww.y; w2v[mt][2] = ww.z; w2v[mt][3] = ww.w;
            } else {
                const ushort4 ww = *(const ushort4*)((const ushort*)w2p + idx);
                union { unsigned int i; float f; } c0, c1, c2, c3;
                c0.i = ((unsigned int)ww.x) << 16; c1.i = ((unsigned int)ww.y) << 16;
                c2.i = ((unsigned int)ww.z) << 16; c3.i = ((unsigned int)ww.w) << 16;
                w2v[mt][0] = c0.f; w2v[mt][1] = c1.f; w2v[mt][2] = c2.f; w2v[mt][3] = c3.f;
            }
        }

        float psum[4] = {0.f, 0.f, 0.f, 0.f};

        #pragma unroll
        for (int mt = 0; mt < 4; ++mt) {
            // 8 MFMAs for this h-slice: acc[nt] = Hid^T tile rows mt*16+quad*4..+3
            floatx4 acc[4];
            #pragma unroll
            for (int nt = 0; nt < 4; ++nt) acc[nt] = (floatx4){0.f, 0.f, 0.f, 0.f};
            #pragma unroll
            for (int ks = 0; ks < 2; ++ks)
                #pragma unroll
                for (int nt = 0; nt < 4; ++nt)
                    acc[nt] = __builtin_amdgcn_mfma_f32_16x16x32_bf16(
                        w[ks][mt], xfrag[ks][nt], acc[nt], 0, 0, 0);

            // w[*][mt] is dead now: prefetch next node's slice into it.
            // (np==7: redundant in-bounds reload, data unused.)
            loadW1mt(nextnode, mt);

            // epilogue for this slice: psum[nt] += sum_r relu(acc[nt][r])*W2[h]
            #pragma unroll
            for (int nt = 0; nt < 4; ++nt) {
                float a0 = acc[nt][0]; a0 = a0 > 0.f ? a0 : 0.f;
                float a1 = acc[nt][1]; a1 = a1 > 0.f ? a1 : 0.f;
                float a2 = acc[nt][2]; a2 = a2 > 0.f ? a2 : 0.f;
                float a3 = acc[nt][3]; a3 = a3 > 0.f ? a3 : 0.f;
                float s0 = fmaf(a0, w2v[mt][0], psum[nt]);
                float s1 = a1 * w2v[mt][1];
                s0 = fmaf(a2, w2v[mt][2], s0);
                s1 = fmaf(a3, w2v[mt][3], s1);
                psum[nt] = s0 + s1;
            }
        }

        // reduce across the 4 quads (same batch col, different h ranges)
        #pragma unroll
        for (int nt = 0; nt < 4; ++nt) {
            psum[nt] += __shfl_xor(psum[nt], 16, 64);
            psum[nt] += __shfl_xor(psum[nt], 32, 64);
        }

        // lane's batch row == lane (nt = quad, col = l16): select psum[quad]
        const float val = (quad == 0) ? psum[0] : (quad == 1) ? psum[1]
                         : (quad == 2) ? psum[2] : psum[3];
        outTile[lane * OTW + (node & 31)] = val;   // lane-major: 2-way aliasing only
    }

    __syncthreads();   // all 32 out-tile columns written

    // ---- output: thread -> (row = tid>>2, eighth q = tid&3); each thread
    // writes 32B contiguous: out[b0+row][nhalf*32 + q*8 .. +7]
    const int row = tid >> 2;
    const int q   = tid & 3;
    const float* rp = outTile + row * OTW + q * 8;
    const size_t obase = (size_t)(b0 + row) * NN + nhalf * 32 + q * 8;
    if (F32) {
        float* op = (float*)outp + obase;
        *(float4*)(op)     = make_float4(rp[0], rp[1], rp[2], rp[3]);
        *(float4*)(op + 4) = make_float4(rp[4], rp[5], rp[6], rp[7]);
    } else {
        ushort* op = (ushort*)outp + obase;
        short8 o;
        #pragma unroll
        for (int c = 0; c < 8; ++c) o[c] = (short)f32_to_bf16_bits(rp[c]);
        *(short8*)(op) = o;
    }
}

__global__ __launch_bounds__(256, 4)
void main_kernel(const void* __restrict__ xorig,
                 const ushort* __restrict__ xo, const ushort* __restrict__ w1o,
                 const void* __restrict__ w2p, void* __restrict__ outp)
{
    __shared__ float outTile[64 * OTW];   // 8.25 KB
    const bool is_bf16 = sniff_bf16(xorig);
    if (is_bf16) main_body<false>(xo, w1o, w2p, outp, outTile);
    else         main_body<true >(xo, w1o, w2p, outp, outTile);
}

// ---------------- fallback: round-6 proven single kernel ----------------------
#define LDSW 20
template<bool F32>
__device__ __forceinline__ void run_body_fb(const void* xp, const void* w1p,
                                            const void* w2p, void* outp,
                                            float* myLds)
{
    const int tid  = threadIdx.x;
    const int wave = tid >> 6;
    const int lane = tid & 63;
    const int quad = lane >> 4;
    const int l16  = lane & 15;
    const int blk  = blockIdx.x;
    const int ng   = blk >> 7;
    const int rbg  = blk & 127;
    const int node = ng * 4 + wave;
    const int rowbase = rbg * 256;

    short8 bfrag[2][4];
    #pragma unroll
    for (int ks = 0; ks < 2; ++ks) {
        #pragma unroll
        for (int ht = 0; ht < 4; ++ht) {
            const int h = ht * 16 + l16;
            const int k = ks * 32 + quad * 8;
            short8 v;
            if (F32) {
                const float* p = (const float*)w1p + node * (HH * NN) + h * NN + k;
                const float4 a0 = *(const float4*)(p);
                const float4 a1 = *(const float4*)(p + 4);
                const float vals[8] = {a0.x, a0.y, a0.z, a0.w, a1.x, a1.y, a1.z, a1.w};
                #pragma unroll
                for (int j = 0; j < 8; ++j) v[j] = (short)f32_to_bf16_bits(vals[j]);
            } else {
                v = *(const short8*)((const ushort*)w1p + node * (HH * NN) + h * NN + k);
            }
            if (node == NN - 1) {
                #pragma unroll
                for (int j = 0; j < 8; ++j)
                    if (k + j != NN - 1) v[j] = 0;
            }
            bfrag[ks][ht] = v;
        }
    }

    float w2reg[4];
    #pragma unroll
    for (int ht = 0; ht < 4; ++ht) {
        const int idx = node * HH + ht * 16 + l16;
        if (F32) {
            w2reg[ht] = ((const float*)w2p)[idx];
        } else {
            const ushort u = ((const ushort*)w2p)[idx];
            union { unsigned int i; float f; } cv; cv.i = ((unsigned int)u) << 16;
            w2reg[ht] = cv.f;
        }
    }

    #pragma unroll 1
    for (int it = 0; it < 4; ++it) {
        const int b0 = rowbase + it * 64;
        short8 afrag[2][4];
        #pragma unroll
        for (int ks = 0; ks < 2; ++ks) {
            #pragma unroll
            for (int rt = 0; rt < 4; ++rt) {
                const int rowg = b0 + rt * 16 + l16;
                const int k    = ks * 32 + quad * 8;
                const bool gate = (ks == 0 && quad < 2);
                short8 v;
                if (F32) {
                    const float* p = (const float*)xp + rowg * NN + k;
                    const float4 a0 = *(const float4*)(p);
                    const float4 a1 = *(const float4*)(p + 4);
                    const float vals[8] = {a0.x, a0.y, a0.z, a0.w, a1.x, a1.y, a1.z, a1.w};
                    #pragma unroll
                    for (int j = 0; j < 8; ++j) {
                        if (gate) v[j] = (vals[j] > 0.f) ? (short)0x3F80 : (short)0;
                        else      v[j] = (short)f32_to_bf16_bits(vals[j]);
                    }
                } else {
                    v = *(const short8*)((const ushort*)xp + rowg * NN + k);
                    if (gate) {
                        #pragma unroll
                        for (int j = 0; j < 8; ++j) {
                            const unsigned short u = (unsigned short)v[j];
                            const bool pos = ((u & 0x8000u) == 0) && ((u & 0x7fffu) != 0);
                            v[j] = pos ? (short)0x3F80 : (short)0;
                        }
                    }
                }
                afrag[ks][rt] = v;
            }
        }

        floatx4 acc[4][4];
        #pragma unroll
        for (int rt = 0; rt < 4; ++rt)
            #pragma unroll
            for (int ht = 0; ht < 4; ++ht)
                acc[rt][ht] = (floatx4){0.f, 0.f, 0.f, 0.f};
        #pragma unroll
        for (int ks = 0; ks < 2; ++ks)
            #pragma unroll
            for (int rt = 0; rt < 4; ++rt)
                #pragma unroll
                for (int ht = 0; ht < 4; ++ht)
                    acc[rt][ht] = __builtin_amdgcn_mfma_f32_16x16x32_bf16(
                        afrag[ks][rt], bfrag[ks][ht], acc[rt][ht], 0, 0, 0);

        #pragma unroll
        for (int rt = 0; rt < 4; ++rt) {
            #pragma unroll
            for (int r = 0; r < 4; ++r) {
                float s = 0.f;
                #pragma unroll
                for (int ht = 0; ht < 4; ++ht) {
                    float v = acc[rt][ht][r];
                    v = v > 0.f ? v : 0.f;
                    s = fmaf(v, w2reg[ht], s);
                }
                myLds[(rt * 16 + quad * 4 + r) * LDSW + l16] = s;
            }
        }
        __syncthreads();
        const float* rowp = myLds + lane * LDSW;
        const float4 v0 = *(const float4*)(rowp + 0);
        const float4 v1 = *(const float4*)(rowp + 4);
        const float4 v2 = *(const float4*)(rowp + 8);
        const float4 v3 = *(const float4*)(rowp + 12);
        const float tot = (((v0.x + v0.y) + (v0.z + v0.w)) + ((v1.x + v1.y) + (v1.z + v1.w)))
                        + (((v2.x + v2.y) + (v2.z + v2.w)) + ((v3.x + v3.y) + (v3.z + v3.w)));
        if (F32) ((float*) outp)[(size_t)(b0 + lane) * NN + node] = tot;
        else     ((ushort*)outp)[(size_t)(b0 + lane) * NN + node] = f32_to_bf16_bits(tot);
        __syncthreads();
    }
}

__global__ __launch_bounds__(256, 2)
void fallback_kernel(const void* __restrict__ x, const void* __restrict__ W1,
                     const void* __restrict__ W2, void* __restrict__ out)
{
    __shared__ float lds[4][64 * LDSW];
    const bool is_bf16 = sniff_bf16(x);
    float* myLds = &lds[threadIdx.x >> 6][0];
    if (is_bf16) run_body_fb<false>(x, W1, W2, out, myLds);
    else         run_body_fb<true >(x, W1, W2, out, myLds);
}

extern "C" void kernel_launch(void* const* d_in, const int* in_sizes, int n_in,
                              void* d_out, int out_size, void* d_ws, size_t ws_size,
                              hipStream_t stream) {
    // Resolve inputs by element count (robust to the scalar t being dropped):
    //   inputs = 2097152, W1 = 262144, W2 = first 4096 (adjacency is the other 4096).
    int i_in = -1, i_w1 = -1, i_w2 = -1;
    for (int i = 0; i < n_in; ++i) {
        const int s = in_sizes[i];
        if      (s == BB * NN  && i_in < 0) i_in = i;
        else if (s == NN*HH*NN && i_w1 < 0) i_w1 = i;
        else if (s == NN*HH    && i_w2 < 0) i_w2 = i;
    }
    if (i_in < 0) i_in = (n_in > 1) ? 1 : 0;
    if (i_w1 < 0) i_w1 = i_in + 1;
    if (i_w2 < 0) i_w2 = i_w1 + 1;

    const size_t need = (size_t)(X_ELEMS + W1_ELEMS) * sizeof(ushort);  // 4.5 MiB
    if (ws_size >= need) {
        ushort* xo  = (ushort*)d_ws;
        ushort* w1o = xo + X_ELEMS;
        prep_kernel<<<dim3((X_ELEMS + W1_ELEMS) / (256 * 8)), dim3(256), 0, stream>>>(
            d_in[i_in], d_in[i_w1], xo, w1o);
        main_kernel<<<dim3(1024), dim3(256), 0, stream>>>(
            d_in[i_in], xo, w1o, d_in[i_w2], d_out);
    } else {
        fallback_kernel<<<dim3(16 * 128), dim3(256), 0, stream>>>(
            d_in[i_in], d_in[i_w1], d_in[i_w2], d_out);
    }
}

// Round 5
// 102.835 us; speedup vs baseline: 1.1238x; 1.1067x over previous
//
#include <hip/hip_runtime.h>
#include <stdint.h>

// CausalDerivative: out[b,i] = sum_h W2[i,h] * relu(sum_n x[b,n]*W1[i,h,n]*M[i,n])
//   x[b,n] = (n<16) ? (inputs[b,n]>0 ? 1 : 0) : inputs[b,n]
//   M = ones, except row 63 keeps only n==63
// B=32768, N=64, H=64. Device tensors FP32 (proven r3/6/7); dual-path kept.
//
// Round 17: r16 post-mortem: occupancy 18->32% (VGPR 64) but dur 50->48us.
// Time invariant to occupancy + all counted pipes idle (MFMA 13, VALU 29,
// HBM 3.6, LDS 0) -> per-CU vector-memory ADDRESS pipe is the limiter:
// ~136 gather-pattern loads/wave (W1: 64 lanes x 16B scattered over 16
// cache lines at 128B stride, ~16-32 TA cycles each). Fix: prep now writes
// W1 in MFMA-fragment order w1s[node][frag=ks*4+mt][lane][8] so every W1
// load in main is one contiguous 1KB wave load (TA-minimal). Scatter cost
// paid once in prep's writes (512 waves) instead of per-node in main.

typedef __attribute__((ext_vector_type(8))) short short8;   // 8 bf16
typedef __attribute__((ext_vector_type(4))) float floatx4;  // MFMA acc

#define NN 64
#define HH 64
#define BB 32768
#define OTW 33    // out-tile row stride in floats (odd -> conflict-benign)
#define X_ELEMS (BB * NN)        // 2097152
#define W1_ELEMS (NN * HH * NN)  // 262144

__device__ __forceinline__ unsigned short f32_to_bf16_bits(float f) {
    union { float f; unsigned int i; } c; c.f = f;
    unsigned int b = c.i;
    b += 0x7fffu + ((b >> 16) & 1u);   // RNE
    return (unsigned short)(b >> 16);
}

__device__ __forceinline__ bool sniff_bf16(const void* x) {
    // bf16 N(0,1): exponent field in [118,132] ~99%; fp32 low-mantissa halves ~6%.
    const int lane = threadIdx.x & 63;
    const ushort* xw = (const ushort*)x;
    const ushort a = xw[4 * lane];
    const ushort b = xw[4 * lane + 2];
    const int ea = (a >> 7) & 0xFF, eb = (b >> 7) & 0xFF;
    const int hit = ((ea >= 118 && ea <= 132) ? 1 : 0) + ((eb >= 118 && eb <= 132) ? 1 : 0);
    const unsigned long long m1 = __ballot(hit >= 1);
    const unsigned long long m2 = __ballot(hit >= 2);
    return (__popcll(m1) + __popcll(m2)) >= 64;
}

// ---------------- prep: gate+convert x; mask+convert+SWIZZLE W1 ---------------
// W1 workspace layout (fragment order): for node i, frag f = ks*4+mt (8 frags),
// lane l = quad*16+l16, elem e:  w1s[i*4096 + f*512 + l*8 + e]
//   holds W1[i][h = mt*16+l16][k = ks*32+quad*8+e]  (bf16, node-63 masked).
__global__ __launch_bounds__(256, 4)
void prep_kernel(const void* __restrict__ x, const void* __restrict__ w1,
                 ushort* __restrict__ xo, ushort* __restrict__ w1s)
{
    const bool is_bf16 = sniff_bf16(x);
    const long base = ((long)blockIdx.x * 256 + (long)threadIdx.x) * 8;

    if (base < X_ELEMS) {
        const bool gate = (base & 63) < 16;   // uniform per 8-elem chunk
        short8 v;
        if (is_bf16) {
            v = *(const short8*)((const ushort*)x + base);
            if (gate) {
                #pragma unroll
                for (int j = 0; j < 8; ++j) {
                    const unsigned short u = (unsigned short)v[j];
                    const bool pos = ((u & 0x8000u) == 0) && ((u & 0x7fffu) != 0);
                    v[j] = pos ? (short)0x3F80 : (short)0;
                }
            }
        } else {
            const float* p = (const float*)x + base;
            const float4 f0 = *(const float4*)(p);
            const float4 f1 = *(const float4*)(p + 4);
            const float vals[8] = {f0.x, f0.y, f0.z, f0.w, f1.x, f1.y, f1.z, f1.w};
            #pragma unroll
            for (int j = 0; j < 8; ++j) {
                if (gate) v[j] = (vals[j] > 0.f) ? (short)0x3F80 : (short)0;
                else      v[j] = (short)f32_to_bf16_bits(vals[j]);
            }
        }
        *(short8*)(xo + base) = v;
    } else {
        const long wb = base - X_ELEMS;
        if (wb < W1_ELEMS) {
            short8 v;
            if (is_bf16) {
                v = *(const short8*)((const ushort*)w1 + wb);
            } else {
                const float* p = (const float*)w1 + wb;
                const float4 f0 = *(const float4*)(p);
                const float4 f1 = *(const float4*)(p + 4);
                const float vals[8] = {f0.x, f0.y, f0.z, f0.w, f1.x, f1.y, f1.z, f1.w};
                #pragma unroll
                for (int j = 0; j < 8; ++j) v[j] = (short)f32_to_bf16_bits(vals[j]);
            }
            // original linear coords of this 8-elem chunk
            const int node = (int)(wb >> 12);        // 4096 elems per node
            const int rem  = (int)(wb & 4095);
            const int h    = rem >> 6;               // 0..63
            const int j8   = (rem >> 3) & 7;         // which 8-col chunk, 0..7
            if (node == NN - 1) {                    // hidden node: keep only k==63
                const int k0 = j8 * 8;
                #pragma unroll
                for (int j = 0; j < 8; ++j)
                    if (k0 + j != NN - 1) v[j] = 0;
            }
            // fragment-order destination
            const int ks   = j8 >> 2;                // 0..1
            const int quad = j8 & 3;                 // 0..3
            const int mt   = h >> 4;                 // 0..3
            const int l16  = h & 15;                 // 0..15
            const long dst = (long)node * 4096 + (ks * 4 + mt) * 512
                           + (quad * 16 + l16) * 8;
            *(short8*)(w1s + dst) = v;
        }
    }
}

// ---------------- main: 64 rows x 32 nodes per block, 8 nodes/wave ------------
// Register-lean (r16) + fragment-order W1 (r17): every W1 load is a
// contiguous 1KB wave load. acc[4] per mt-slice; per-mt-slice prefetch of
// the next node into the just-consumed registers.
template<bool F32>
__device__ __forceinline__ void main_body(const ushort* __restrict__ xo,
                                          const ushort* __restrict__ w1s,
                                          const void* __restrict__ w2p,
                                          void* __restrict__ outp,
                                          float* outTile)
{
    const int tid  = threadIdx.x;
    const int wave = tid >> 6;
    const int lane = tid & 63;
    const int quad = lane >> 4;   // 0..3
    const int l16  = lane & 15;   // 0..15

    const int blk   = blockIdx.x;        // 0..1023
    const int b0    = (blk >> 1) * 64;   // this block's 64 batch rows
    const int nhalf = blk & 1;           // which 32-node half
    const int nbase = nhalf * 32 + wave * 8;  // this wave's 8 nodes (global ids)

    // ---- x fragments, loaded ONCE, reused by 8 node-GEMMs. Role: MFMA *B*
    //      B[k][bcol] = xo[b0+bcol][k]; bcol = nt*16+l16, k = ks*32+quad*8+j
    //      (gather pattern, but only 8 instrs per wave total — negligible TA)
    short8 xfrag[2][4];
    #pragma unroll
    for (int ks = 0; ks < 2; ++ks)
        #pragma unroll
        for (int nt = 0; nt < 4; ++nt)
            xfrag[ks][nt] = *(const short8*)(xo + (b0 + nt * 16 + l16) * NN + ks * 32 + quad * 8);

    // ---- W1 fragment loads from swizzled layout: contiguous per wave.
    //      frag f = ks*4+mt at  node*4096 + f*512 + lane*8
    short8 w[2][4];
    auto loadW1mt = [&](int node, int mt) {
        const ushort* p = w1s + (long)node * 4096 + mt * 512 + lane * 8;
        w[0][mt] = *(const short8*)(p);          // ks=0 frag
        w[1][mt] = *(const short8*)(p + 2048);   // ks=1 frag (f = 4+mt)
    };

    // preload node 0's four slices
    #pragma unroll
    for (int mt = 0; mt < 4; ++mt) loadW1mt(nbase, mt);

    #pragma unroll 1
    for (int np = 0; np < 8; ++np) {
        const int node = nbase + np;
        const int nextnode = (np < 7) ? (node + 1) : node;  // clamp: in-bounds dummy

        // W2 for this node (16 regs, consumed per mt-epilogue); broadcast loads
        float w2v[4][4];
        #pragma unroll
        for (int mt = 0; mt < 4; ++mt) {
            const int idx = node * HH + mt * 16 + quad * 4;
            if (F32) {
                const float4 ww = *(const float4*)((const float*)w2p + idx);
                w2v[mt][0] = ww.x; w2v[mt][1] = ww.y; w2v[mt][2] = ww.z; w2v[mt][3] = ww.w;
            } else {
                const ushort4 ww = *(const ushort4*)((const ushort*)w2p + idx);
                union { unsigned int i; float f; } c0, c1, c2, c3;
                c0.i = ((unsigned int)ww.x) << 16; c1.i = ((unsigned int)ww.y) << 16;
                c2.i = ((unsigned int)ww.z) << 16; c3.i = ((unsigned int)ww.w) << 16;
                w2v[mt][0] = c0.f; w2v[mt][1] = c1.f; w2v[mt][2] = c2.f; w2v[mt][3] = c3.f;
            }
        }

        float psum[4] = {0.f, 0.f, 0.f, 0.f};

        #pragma unroll
        for (int mt = 0; mt < 4; ++mt) {
            // 8 MFMAs for this h-slice: acc[nt] = Hid^T tile rows mt*16+quad*4..+3
            floatx4 acc[4];
            #pragma unroll
            for (int nt = 0; nt < 4; ++nt) acc[nt] = (floatx4){0.f, 0.f, 0.f, 0.f};
            #pragma unroll
            for (int ks = 0; ks < 2; ++ks)
                #pragma unroll
                for (int nt = 0; nt < 4; ++nt)
                    acc[nt] = __builtin_amdgcn_mfma_f32_16x16x32_bf16(
                        w[ks][mt], xfrag[ks][nt], acc[nt], 0, 0, 0);

            // w[*][mt] is dead now: prefetch next node's slice into it.
            // (np==7: redundant in-bounds reload, data unused.)
            loadW1mt(nextnode, mt);

            // epilogue for this slice: psum[nt] += sum_r relu(acc[nt][r])*W2[h]
            #pragma unroll
            for (int nt = 0; nt < 4; ++nt) {
                float a0 = acc[nt][0]; a0 = a0 > 0.f ? a0 : 0.f;
                float a1 = acc[nt][1]; a1 = a1 > 0.f ? a1 : 0.f;
                float a2 = acc[nt][2]; a2 = a2 > 0.f ? a2 : 0.f;
                float a3 = acc[nt][3]; a3 = a3 > 0.f ? a3 : 0.f;
                float s0 = fmaf(a0, w2v[mt][0], psum[nt]);
                float s1 = a1 * w2v[mt][1];
                s0 = fmaf(a2, w2v[mt][2], s0);
                s1 = fmaf(a3, w2v[mt][3], s1);
                psum[nt] = s0 + s1;
            }
        }

        // reduce across the 4 quads (same batch col, different h ranges)
        #pragma unroll
        for (int nt = 0; nt < 4; ++nt) {
            psum[nt] += __shfl_xor(psum[nt], 16, 64);
            psum[nt] += __shfl_xor(psum[nt], 32, 64);
        }

        // lane's batch row == lane (nt = quad, col = l16): select psum[quad]
        const float val = (quad == 0) ? psum[0] : (quad == 1) ? psum[1]
                         : (quad == 2) ? psum[2] : psum[3];
        outTile[lane * OTW + (node & 31)] = val;   // lane-major: 2-way aliasing only
    }

    __syncthreads();   // all 32 out-tile columns written

    // ---- output: thread -> (row = tid>>2, eighth q = tid&3); each thread
    // writes 32B contiguous: out[b0+row][nhalf*32 + q*8 .. +7]
    const int row = tid >> 2;
    const int q   = tid & 3;
    const float* rp = outTile + row * OTW + q * 8;
    const size_t obase = (size_t)(b0 + row) * NN + nhalf * 32 + q * 8;
    if (F32) {
        float* op = (float*)outp + obase;
        *(float4*)(op)     = make_float4(rp[0], rp[1], rp[2], rp[3]);
        *(float4*)(op + 4) = make_float4(rp[4], rp[5], rp[6], rp[7]);
    } else {
        ushort* op = (ushort*)outp + obase;
        short8 o;
        #pragma unroll
        for (int c = 0; c < 8; ++c) o[c] = (short)f32_to_bf16_bits(rp[c]);
        *(short8*)(op) = o;
    }
}

__global__ __launch_bounds__(256, 4)
void main_kernel(const void* __restrict__ xorig,
                 const ushort* __restrict__ xo, const ushort* __restrict__ w1s,
                 const void* __restrict__ w2p, void* __restrict__ outp)
{
    __shared__ float outTile[64 * OTW];   // 8.25 KB
    const bool is_bf16 = sniff_bf16(xorig);
    if (is_bf16) main_body<false>(xo, w1s, w2p, outp, outTile);
    else         main_body<true >(xo, w1s, w2p, outp, outTile);
}

// ---------------- fallback: round-6 proven single kernel ----------------------
#define LDSW 20
template<bool F32>
__device__ __forceinline__ void run_body_fb(const void* xp, const void* w1p,
                                            const void* w2p, void* outp,
                                            float* myLds)
{
    const int tid  = threadIdx.x;
    const int wave = tid >> 6;
    const int lane = tid & 63;
    const int quad = lane >> 4;
    const int l16  = lane & 15;
    const int blk  = blockIdx.x;
    const int ng   = blk >> 7;
    const int rbg  = blk & 127;
    const int node = ng * 4 + wave;
    const int rowbase = rbg * 256;

    short8 bfrag[2][4];
    #pragma unroll
    for (int ks = 0; ks < 2; ++ks) {
        #pragma unroll
        for (int ht = 0; ht < 4; ++ht) {
            const int h = ht * 16 + l16;
            const int k = ks * 32 + quad * 8;
            short8 v;
            if (F32) {
                const float* p = (const float*)w1p + node * (HH * NN) + h * NN + k;
                const float4 a0 = *(const float4*)(p);
                const float4 a1 = *(const float4*)(p + 4);
                const float vals[8] = {a0.x, a0.y, a0.z, a0.w, a1.x, a1.y, a1.z, a1.w};
                #pragma unroll
                for (int j = 0; j < 8; ++j) v[j] = (short)f32_to_bf16_bits(vals[j]);
            } else {
                v = *(const short8*)((const ushort*)w1p + node * (HH * NN) + h * NN + k);
            }
            if (node == NN - 1) {
                #pragma unroll
                for (int j = 0; j < 8; ++j)
                    if (k + j != NN - 1) v[j] = 0;
            }
            bfrag[ks][ht] = v;
        }
    }

    float w2reg[4];
    #pragma unroll
    for (int ht = 0; ht < 4; ++ht) {
        const int idx = node * HH + ht * 16 + l16;
        if (F32) {
            w2reg[ht] = ((const float*)w2p)[idx];
        } else {
            const ushort u = ((const ushort*)w2p)[idx];
            union { unsigned int i; float f; } cv; cv.i = ((unsigned int)u) << 16;
            w2reg[ht] = cv.f;
        }
    }

    #pragma unroll 1
    for (int it = 0; it < 4; ++it) {
        const int b0 = rowbase + it * 64;
        short8 afrag[2][4];
        #pragma unroll
        for (int ks = 0; ks < 2; ++ks) {
            #pragma unroll
            for (int rt = 0; rt < 4; ++rt) {
                const int rowg = b0 + rt * 16 + l16;
                const int k    = ks * 32 + quad * 8;
                const bool gate = (ks == 0 && quad < 2);
                short8 v;
                if (F32) {
                    const float* p = (const float*)xp + rowg * NN + k;
                    const float4 a0 = *(const float4*)(p);
                    const float4 a1 = *(const float4*)(p + 4);
                    const float vals[8] = {a0.x, a0.y, a0.z, a0.w, a1.x, a1.y, a1.z, a1.w};
                    #pragma unroll
                    for (int j = 0; j < 8; ++j) {
                        if (gate) v[j] = (vals[j] > 0.f) ? (short)0x3F80 : (short)0;
                        else      v[j] = (short)f32_to_bf16_bits(vals[j]);
                    }
                } else {
                    v = *(const short8*)((const ushort*)xp + rowg * NN + k);
                    if (gate) {
                        #pragma unroll
                        for (int j = 0; j < 8; ++j) {
                            const unsigned short u = (unsigned short)v[j];
                            const bool pos = ((u & 0x8000u) == 0) && ((u & 0x7fffu) != 0);
                            v[j] = pos ? (short)0x3F80 : (short)0;
                        }
                    }
                }
                afrag[ks][rt] = v;
            }
        }

        floatx4 acc[4][4];
        #pragma unroll
        for (int rt = 0; rt < 4; ++rt)
            #pragma unroll
            for (int ht = 0; ht < 4; ++ht)
                acc[rt][ht] = (floatx4){0.f, 0.f, 0.f, 0.f};
        #pragma unroll
        for (int ks = 0; ks < 2; ++ks)
            #pragma unroll
            for (int rt = 0; rt < 4; ++rt)
                #pragma unroll
                for (int ht = 0; ht < 4; ++ht)
                    acc[rt][ht] = __builtin_amdgcn_mfma_f32_16x16x32_bf16(
                        afrag[ks][rt], bfrag[ks][ht], acc[rt][ht], 0, 0, 0);

        #pragma unroll
        for (int rt = 0; rt < 4; ++rt) {
            #pragma unroll
            for (int r = 0; r < 4; ++r) {
                float s = 0.f;
                #pragma unroll
                for (int ht = 0; ht < 4; ++ht) {
                    float v = acc[rt][ht][r];
                    v = v > 0.f ? v : 0.f;
                    s = fmaf(v, w2reg[ht], s);
                }
                myLds[(rt * 16 + quad * 4 + r) * LDSW + l16] = s;
            }
        }
        __syncthreads();
        const float* rowp = myLds + lane * LDSW;
        const float4 v0 = *(const float4*)(rowp + 0);
        const float4 v1 = *(const float4*)(rowp + 4);
        const float4 v2 = *(const float4*)(rowp + 8);
        const float4 v3 = *(const float4*)(rowp + 12);
        const float tot = (((v0.x + v0.y) + (v0.z + v0.w)) + ((v1.x + v1.y) + (v1.z + v1.w)))
                        + (((v2.x + v2.y) + (v2.z + v2.w)) + ((v3.x + v3.y) + (v3.z + v3.w)));
        if (F32) ((float*) outp)[(size_t)(b0 + lane) * NN + node] = tot;
        else     ((ushort*)outp)[(size_t)(b0 + lane) * NN + node] = f32_to_bf16_bits(tot);
        __syncthreads();
    }
}

__global__ __launch_bounds__(256, 2)
void fallback_kernel(const void* __restrict__ x, const void* __restrict__ W1,
                     const void* __restrict__ W2, void* __restrict__ out)
{
    __shared__ float lds[4][64 * LDSW];
    const bool is_bf16 = sniff_bf16(x);
    float* myLds = &lds[threadIdx.x >> 6][0];
    if (is_bf16) run_body_fb<false>(x, W1, W2, out, myLds);
    else         run_body_fb<true >(x, W1, W2, out, myLds);
}

extern "C" void kernel_launch(void* const* d_in, const int* in_sizes, int n_in,
                              void* d_out, int out_size, void* d_ws, size_t ws_size,
                              hipStream_t stream) {
    // Resolve inputs by element count (robust to the scalar t being dropped):
    //   inputs = 2097152, W1 = 262144, W2 = first 4096 (adjacency is the other 4096).
    int i_in = -1, i_w1 = -1, i_w2 = -1;
    for (int i = 0; i < n_in; ++i) {
        const int s = in_sizes[i];
        if      (s == BB * NN  && i_in < 0) i_in = i;
        else if (s == NN*HH*NN && i_w1 < 0) i_w1 = i;
        else if (s == NN*HH    && i_w2 < 0) i_w2 = i;
    }
    if (i_in < 0) i_in = (n_in > 1) ? 1 : 0;
    if (i_w1 < 0) i_w1 = i_in + 1;
    if (i_w2 < 0) i_w2 = i_w1 + 1;

    const size_t need = (size_t)(X_ELEMS + W1_ELEMS) * sizeof(ushort);  // 4.5 MiB
    if (ws_size >= need) {
        ushort* xo  = (ushort*)d_ws;
        ushort* w1s = xo + X_ELEMS;
        prep_kernel<<<dim3((X_ELEMS + W1_ELEMS) / (256 * 8)), dim3(256), 0, stream>>>(
            d_in[i_in], d_in[i_w1], xo, w1s);
        main_kernel<<<dim3(1024), dim3(256), 0, stream>>>(
            d_in[i_in], xo, w1s, d_in[i_w2], d_out);
    } else {
        fallback_kernel<<<dim3(16 * 128), dim3(256), 0, stream>>>(
            d_in[i_in], d_in[i_w1], d_in[i_w2], d_out);
    }
}

// Round 6
// 98.400 us; speedup vs baseline: 1.1744x; 1.0451x over previous
//
#include <hip/hip_runtime.h>
#include <stdint.h>

// CausalDerivative: out[b,i] = sum_h W2[i,h] * relu(sum_n x[b,n]*W1[i,h,n]*M[i,n])
//   x[b,n] = (n<16) ? (inputs[b,n]>0 ? 1 : 0) : inputs[b,n]
//   M = ones, except row 63 keeps only n==63
// B=32768, N=64, H=64. Device tensors FP32 (proven r3/6/7); dual-path kept.
//
// Round 18: r17 post-mortem: fragment-order W1 dropped main below the 46us
// harness fill (total 113.8->102.8, main ~37us inferred). Remaining theory:
// (a) W2 global loads at each node-iter head have no prefetch pipeline ->
// fresh ~200-500cy L2 latency per iter; (b) prep's x-pass (12.6MB r/w) is
// redundant — fallback proves inline gating. Fixes: stage W2 in LDS once
// per block (8KB; per-iter reads become ds_read_b128 broadcasts) and gate
// x inline in main (prep is now W1-only, 0.5MB, 128 blocks).

typedef __attribute__((ext_vector_type(8))) short short8;   // 8 bf16
typedef __attribute__((ext_vector_type(4))) float floatx4;  // MFMA acc

#define NN 64
#define HH 64
#define BB 32768
#define OTW 33    // out-tile row stride in floats (odd -> conflict-benign)
#define X_ELEMS (BB * NN)        // 2097152
#define W1_ELEMS (NN * HH * NN)  // 262144

__device__ __forceinline__ unsigned short f32_to_bf16_bits(float f) {
    union { float f; unsigned int i; } c; c.f = f;
    unsigned int b = c.i;
    b += 0x7fffu + ((b >> 16) & 1u);   // RNE
    return (unsigned short)(b >> 16);
}

__device__ __forceinline__ bool sniff_bf16(const void* x) {
    // bf16 N(0,1): exponent field in [118,132] ~99%; fp32 low-mantissa halves ~6%.
    const int lane = threadIdx.x & 63;
    const ushort* xw = (const ushort*)x;
    const ushort a = xw[4 * lane];
    const ushort b = xw[4 * lane + 2];
    const int ea = (a >> 7) & 0xFF, eb = (b >> 7) & 0xFF;
    const int hit = ((ea >= 118 && ea <= 132) ? 1 : 0) + ((eb >= 118 && eb <= 132) ? 1 : 0);
    const unsigned long long m1 = __ballot(hit >= 1);
    const unsigned long long m2 = __ballot(hit >= 2);
    return (__popcll(m1) + __popcll(m2)) >= 64;
}

// ---------------- prep: mask+convert+SWIZZLE W1 only --------------------------
// W1 workspace layout (fragment order): for node i, frag f = ks*4+mt (8 frags),
// lane l = quad*16+l16, elem e:  w1s[i*4096 + f*512 + l*8 + e]
//   holds W1[i][h = mt*16+l16][k = ks*32+quad*8+e]  (bf16, node-63 masked).
__global__ __launch_bounds__(256, 4)
void prep_kernel(const void* __restrict__ x, const void* __restrict__ w1,
                 ushort* __restrict__ w1s)
{
    const bool is_bf16 = sniff_bf16(x);
    const long wb = ((long)blockIdx.x * 256 + (long)threadIdx.x) * 8;
    if (wb >= W1_ELEMS) return;

    short8 v;
    if (is_bf16) {
        v = *(const short8*)((const ushort*)w1 + wb);
    } else {
        const float* p = (const float*)w1 + wb;
        const float4 f0 = *(const float4*)(p);
        const float4 f1 = *(const float4*)(p + 4);
        const float vals[8] = {f0.x, f0.y, f0.z, f0.w, f1.x, f1.y, f1.z, f1.w};
        #pragma unroll
        for (int j = 0; j < 8; ++j) v[j] = (short)f32_to_bf16_bits(vals[j]);
    }
    // original linear coords of this 8-elem chunk
    const int node = (int)(wb >> 12);        // 4096 elems per node
    const int rem  = (int)(wb & 4095);
    const int h    = rem >> 6;               // 0..63
    const int j8   = (rem >> 3) & 7;         // which 8-col chunk, 0..7
    if (node == NN - 1) {                    // hidden node: keep only k==63
        const int k0 = j8 * 8;
        #pragma unroll
        for (int j = 0; j < 8; ++j)
            if (k0 + j != NN - 1) v[j] = 0;
    }
    // fragment-order destination
    const int ks   = j8 >> 2;                // 0..1
    const int quad = j8 & 3;                 // 0..3
    const int mt   = h >> 4;                 // 0..3
    const int l16  = h & 15;                 // 0..15
    const long dst = (long)node * 4096 + (ks * 4 + mt) * 512
                   + (quad * 16 + l16) * 8;
    *(short8*)(w1s + dst) = v;
}

// ---------------- main: 64 rows x 32 nodes per block, 8 nodes/wave ------------
// Register-lean (r16) + fragment-order W1 (r17) + inline x-gating and
// LDS-staged W2 (r18). Every W1 load is a contiguous 1KB wave load; W2 is
// read per node-iter from LDS (broadcast, no global latency).
template<bool F32>
__device__ __forceinline__ void main_body(const void* __restrict__ xp,
                                          const ushort* __restrict__ w1s,
                                          const void* __restrict__ w2p,
                                          void* __restrict__ outp,
                                          float* outTile, float* w2lds)
{
    const int tid  = threadIdx.x;
    const int wave = tid >> 6;
    const int lane = tid & 63;
    const int quad = lane >> 4;   // 0..3
    const int l16  = lane & 15;   // 0..15

    const int blk   = blockIdx.x;        // 0..1023
    const int b0    = (blk >> 1) * 64;   // this block's 64 batch rows
    const int nhalf = blk & 1;           // which 32-node half
    const int nbase = nhalf * 32 + wave * 8;  // this wave's 8 nodes (global ids)

    // ---- stage this block's 32 W2 rows into LDS: w2lds[n'][h], 8KB.
    //      Each thread loads 8 contiguous elems (coalesced).
    {
        const int i8 = tid * 8;              // 0..2040
        const size_t g = (size_t)(nhalf * 32) * HH + i8;
        if (F32) {
            const float* p = (const float*)w2p + g;
            const float4 a0 = *(const float4*)(p);
            const float4 a1 = *(const float4*)(p + 4);
            *(float4*)(w2lds + i8)     = a0;
            *(float4*)(w2lds + i8 + 4) = a1;
        } else {
            const ushort4 u0 = *(const ushort4*)((const ushort*)w2p + g);
            const ushort4 u1 = *(const ushort4*)((const ushort*)w2p + g + 4);
            union { unsigned int i; float f; } c;
            c.i = ((unsigned int)u0.x) << 16; w2lds[i8 + 0] = c.f;
            c.i = ((unsigned int)u0.y) << 16; w2lds[i8 + 1] = c.f;
            c.i = ((unsigned int)u0.z) << 16; w2lds[i8 + 2] = c.f;
            c.i = ((unsigned int)u0.w) << 16; w2lds[i8 + 3] = c.f;
            c.i = ((unsigned int)u1.x) << 16; w2lds[i8 + 4] = c.f;
            c.i = ((unsigned int)u1.y) << 16; w2lds[i8 + 5] = c.f;
            c.i = ((unsigned int)u1.z) << 16; w2lds[i8 + 6] = c.f;
            c.i = ((unsigned int)u1.w) << 16; w2lds[i8 + 7] = c.f;
        }
    }

    // ---- x fragments with INLINE gating, loaded ONCE, reused by 8 node-GEMMs.
    //      Role: MFMA *B*: B[k][bcol] = x[b0+bcol][k] (gated for k<16);
    //      bcol = nt*16+l16, k = ks*32+quad*8+j.  k<16 <=> ks==0 && quad<2.
    short8 xfrag[2][4];
    #pragma unroll
    for (int ks = 0; ks < 2; ++ks) {
        #pragma unroll
        for (int nt = 0; nt < 4; ++nt) {
            const int rowg = b0 + nt * 16 + l16;
            const int k    = ks * 32 + quad * 8;
            const bool gate = (ks == 0 && quad < 2);
            short8 v;
            if (F32) {
                const float* p = (const float*)xp + (size_t)rowg * NN + k;
                const float4 a0 = *(const float4*)(p);
                const float4 a1 = *(const float4*)(p + 4);
                const float vals[8] = {a0.x, a0.y, a0.z, a0.w, a1.x, a1.y, a1.z, a1.w};
                #pragma unroll
                for (int j = 0; j < 8; ++j) {
                    if (gate) v[j] = (vals[j] > 0.f) ? (short)0x3F80 : (short)0;
                    else      v[j] = (short)f32_to_bf16_bits(vals[j]);
                }
            } else {
                v = *(const short8*)((const ushort*)xp + (size_t)rowg * NN + k);
                if (gate) {
                    #pragma unroll
                    for (int j = 0; j < 8; ++j) {
                        const unsigned short u = (unsigned short)v[j];
                        const bool pos = ((u & 0x8000u) == 0) && ((u & 0x7fffu) != 0);
                        v[j] = pos ? (short)0x3F80 : (short)0;
                    }
                }
            }
            xfrag[ks][nt] = v;
        }
    }

    __syncthreads();   // w2lds ready

    // ---- W1 fragment loads from swizzled layout: contiguous per wave.
    //      frag f = ks*4+mt at  node*4096 + f*512 + lane*8
    short8 w[2][4];
    auto loadW1mt = [&](int node, int mt) {
        const ushort* p = w1s + (long)node * 4096 + mt * 512 + lane * 8;
        w[0][mt] = *(const short8*)(p);          // ks=0 frag
        w[1][mt] = *(const short8*)(p + 2048);   // ks=1 frag (f = 4+mt)
    };

    // preload node 0's four slices
    #pragma unroll
    for (int mt = 0; mt < 4; ++mt) loadW1mt(nbase, mt);

    #pragma unroll 1
    for (int np = 0; np < 8; ++np) {
        const int node = nbase + np;
        const int nextnode = (np < 7) ? (node + 1) : node;  // clamp: in-bounds dummy

        // W2 for this node from LDS (broadcast within each quad)
        float w2v[4][4];
        #pragma unroll
        for (int mt = 0; mt < 4; ++mt) {
            const float4 ww = *(const float4*)(w2lds + (node & 31) * HH + mt * 16 + quad * 4);
            w2v[mt][0] = ww.x; w2v[mt][1] = ww.y; w2v[mt][2] = ww.z; w2v[mt][3] = ww.w;
        }

        float psum[4] = {0.f, 0.f, 0.f, 0.f};

        #pragma unroll
        for (int mt = 0; mt < 4; ++mt) {
            // 8 MFMAs for this h-slice: acc[nt] = Hid^T tile rows mt*16+quad*4..+3
            floatx4 acc[4];
            #pragma unroll
            for (int nt = 0; nt < 4; ++nt) acc[nt] = (floatx4){0.f, 0.f, 0.f, 0.f};
            #pragma unroll
            for (int ks = 0; ks < 2; ++ks)
                #pragma unroll
                for (int nt = 0; nt < 4; ++nt)
                    acc[nt] = __builtin_amdgcn_mfma_f32_16x16x32_bf16(
                        w[ks][mt], xfrag[ks][nt], acc[nt], 0, 0, 0);

            // w[*][mt] is dead now: prefetch next node's slice into it.
            // (np==7: redundant in-bounds reload, data unused.)
            loadW1mt(nextnode, mt);

            // epilogue for this slice: psum[nt] += sum_r relu(acc[nt][r])*W2[h]
            #pragma unroll
            for (int nt = 0; nt < 4; ++nt) {
                float a0 = acc[nt][0]; a0 = a0 > 0.f ? a0 : 0.f;
                float a1 = acc[nt][1]; a1 = a1 > 0.f ? a1 : 0.f;
                float a2 = acc[nt][2]; a2 = a2 > 0.f ? a2 : 0.f;
                float a3 = acc[nt][3]; a3 = a3 > 0.f ? a3 : 0.f;
                float s0 = fmaf(a0, w2v[mt][0], psum[nt]);
                float s1 = a1 * w2v[mt][1];
                s0 = fmaf(a2, w2v[mt][2], s0);
                s1 = fmaf(a3, w2v[mt][3], s1);
                psum[nt] = s0 + s1;
            }
        }

        // reduce across the 4 quads (same batch col, different h ranges)
        #pragma unroll
        for (int nt = 0; nt < 4; ++nt) {
            psum[nt] += __shfl_xor(psum[nt], 16, 64);
            psum[nt] += __shfl_xor(psum[nt], 32, 64);
        }

        // lane's batch row == lane (nt = quad, col = l16): select psum[quad]
        const float val = (quad == 0) ? psum[0] : (quad == 1) ? psum[1]
                         : (quad == 2) ? psum[2] : psum[3];
        outTile[lane * OTW + (node & 31)] = val;   // lane-major: 2-way aliasing only
    }

    __syncthreads();   // all 32 out-tile columns written

    // ---- output: thread -> (row = tid>>2, eighth q = tid&3); each thread
    // writes 32B contiguous: out[b0+row][nhalf*32 + q*8 .. +7]
    const int row = tid >> 2;
    const int q   = tid & 3;
    const float* rp = outTile + row * OTW + q * 8;
    const size_t obase = (size_t)(b0 + row) * NN + nhalf * 32 + q * 8;
    if (F32) {
        float* op = (float*)outp + obase;
        *(float4*)(op)     = make_float4(rp[0], rp[1], rp[2], rp[3]);
        *(float4*)(op + 4) = make_float4(rp[4], rp[5], rp[6], rp[7]);
    } else {
        ushort* op = (ushort*)outp + obase;
        short8 o;
        #pragma unroll
        for (int c = 0; c < 8; ++c) o[c] = (short)f32_to_bf16_bits(rp[c]);
        *(short8*)(op) = o;
    }
}

__global__ __launch_bounds__(256, 4)
void main_kernel(const void* __restrict__ x, const ushort* __restrict__ w1s,
                 const void* __restrict__ w2p, void* __restrict__ outp)
{
    __shared__ float outTile[64 * OTW];   // 8.25 KB
    __shared__ float w2lds[32 * HH];      // 8 KB
    const bool is_bf16 = sniff_bf16(x);
    if (is_bf16) main_body<false>(x, w1s, w2p, outp, outTile, w2lds);
    else         main_body<true >(x, w1s, w2p, outp, outTile, w2lds);
}

// ---------------- fallback: round-6 proven single kernel ----------------------
#define LDSW 20
template<bool F32>
__device__ __forceinline__ void run_body_fb(const void* xp, const void* w1p,
                                            const void* w2p, void* outp,
                                            float* myLds)
{
    const int tid  = threadIdx.x;
    const int wave = tid >> 6;
    const int lane = tid & 63;
    const int quad = lane >> 4;
    const int l16  = lane & 15;
    const int blk  = blockIdx.x;
    const int ng   = blk >> 7;
    const int rbg  = blk & 127;
    const int node = ng * 4 + wave;
    const int rowbase = rbg * 256;

    short8 bfrag[2][4];
    #pragma unroll
    for (int ks = 0; ks < 2; ++ks) {
        #pragma unroll
        for (int ht = 0; ht < 4; ++ht) {
            const int h = ht * 16 + l16;
            const int k = ks * 32 + quad * 8;
            short8 v;
            if (F32) {
                const float* p = (const float*)w1p + node * (HH * NN) + h * NN + k;
                const float4 a0 = *(const float4*)(p);
                const float4 a1 = *(const float4*)(p + 4);
                const float vals[8] = {a0.x, a0.y, a0.z, a0.w, a1.x, a1.y, a1.z, a1.w};
                #pragma unroll
                for (int j = 0; j < 8; ++j) v[j] = (short)f32_to_bf16_bits(vals[j]);
            } else {
                v = *(const short8*)((const ushort*)w1p + node * (HH * NN) + h * NN + k);
            }
            if (node == NN - 1) {
                #pragma unroll
                for (int j = 0; j < 8; ++j)
                    if (k + j != NN - 1) v[j] = 0;
            }
            bfrag[ks][ht] = v;
        }
    }

    float w2reg[4];
    #pragma unroll
    for (int ht = 0; ht < 4; ++ht) {
        const int idx = node * HH + ht * 16 + l16;
        if (F32) {
            w2reg[ht] = ((const float*)w2p)[idx];
        } else {
            const ushort u = ((const ushort*)w2p)[idx];
            union { unsigned int i; float f; } cv; cv.i = ((unsigned int)u) << 16;
            w2reg[ht] = cv.f;
        }
    }

    #pragma unroll 1
    for (int it = 0; it < 4; ++it) {
        const int b0 = rowbase + it * 64;
        short8 afrag[2][4];
        #pragma unroll
        for (int ks = 0; ks < 2; ++ks) {
            #pragma unroll
            for (int rt = 0; rt < 4; ++rt) {
                const int rowg = b0 + rt * 16 + l16;
                const int k    = ks * 32 + quad * 8;
                const bool gate = (ks == 0 && quad < 2);
                short8 v;
                if (F32) {
                    const float* p = (const float*)xp + rowg * NN + k;
                    const float4 a0 = *(const float4*)(p);
                    const float4 a1 = *(const float4*)(p + 4);
                    const float vals[8] = {a0.x, a0.y, a0.z, a0.w, a1.x, a1.y, a1.z, a1.w};
                    #pragma unroll
                    for (int j = 0; j < 8; ++j) {
                        if (gate) v[j] = (vals[j] > 0.f) ? (short)0x3F80 : (short)0;
                        else      v[j] = (short)f32_to_bf16_bits(vals[j]);
                    }
                } else {
                    v = *(const short8*)((const ushort*)xp + rowg * NN + k);
                    if (gate) {
                        #pragma unroll
                        for (int j = 0; j < 8; ++j) {
                            const unsigned short u = (unsigned short)v[j];
                            const bool pos = ((u & 0x8000u) == 0) && ((u & 0x7fffu) != 0);
                            v[j] = pos ? (short)0x3F80 : (short)0;
                        }
                    }
                }
                afrag[ks][rt] = v;
            }
        }

        floatx4 acc[4][4];
        #pragma unroll
        for (int rt = 0; rt < 4; ++rt)
            #pragma unroll
            for (int ht = 0; ht < 4; ++ht)
                acc[rt][ht] = (floatx4){0.f, 0.f, 0.f, 0.f};
        #pragma unroll
        for (int ks = 0; ks < 2; ++ks)
            #pragma unroll
            for (int rt = 0; rt < 4; ++rt)
                #pragma unroll
                for (int ht = 0; ht < 4; ++ht)
                    acc[rt][ht] = __builtin_amdgcn_mfma_f32_16x16x32_bf16(
                        afrag[ks][rt], bfrag[ks][ht], acc[rt][ht], 0, 0, 0);

        #pragma unroll
        for (int rt = 0; rt < 4; ++rt) {
            #pragma unroll
            for (int r = 0; r < 4; ++r) {
                float s = 0.f;
                #pragma unroll
                for (int ht = 0; ht < 4; ++ht) {
                    float v = acc[rt][ht][r];
                    v = v > 0.f ? v : 0.f;
                    s = fmaf(v, w2reg[ht], s);
                }
                myLds[(rt * 16 + quad * 4 + r) * LDSW + l16] = s;
            }
        }
        __syncthreads();
        const float* rowp = myLds + lane * LDSW;
        const float4 v0 = *(const float4*)(rowp + 0);
        const float4 v1 = *(const float4*)(rowp + 4);
        const float4 v2 = *(const float4*)(rowp + 8);
        const float4 v3 = *(const float4*)(rowp + 12);
        const float tot = (((v0.x + v0.y) + (v0.z + v0.w)) + ((v1.x + v1.y) + (v1.z + v1.w)))
                        + (((v2.x + v2.y) + (v2.z + v2.w)) + ((v3.x + v3.y) + (v3.z + v3.w)));
        if (F32) ((float*) outp)[(size_t)(b0 + lane) * NN + node] = tot;
        else     ((ushort*)outp)[(size_t)(b0 + lane) * NN + node] = f32_to_bf16_bits(tot);
        __syncthreads();
    }
}

__global__ __launch_bounds__(256, 2)
void fallback_kernel(const void* __restrict__ x, const void* __restrict__ W1,
                     const void* __restrict__ W2, void* __restrict__ out)
{
    __shared__ float lds[4][64 * LDSW];
    const bool is_bf16 = sniff_bf16(x);
    float* myLds = &lds[threadIdx.x >> 6][0];
    if (is_bf16) run_body_fb<false>(x, W1, W2, out, myLds);
    else         run_body_fb<true >(x, W1, W2, out, myLds);
}

extern "C" void kernel_launch(void* const* d_in, const int* in_sizes, int n_in,
                              void* d_out, int out_size, void* d_ws, size_t ws_size,
                              hipStream_t stream) {
    // Resolve inputs by element count (robust to the scalar t being dropped):
    //   inputs = 2097152, W1 = 262144, W2 = first 4096 (adjacency is the other 4096).
    int i_in = -1, i_w1 = -1, i_w2 = -1;
    for (int i = 0; i < n_in; ++i) {
        const int s = in_sizes[i];
        if      (s == BB * NN  && i_in < 0) i_in = i;
        else if (s == NN*HH*NN && i_w1 < 0) i_w1 = i;
        else if (s == NN*HH    && i_w2 < 0) i_w2 = i;
    }
    if (i_in < 0) i_in = (n_in > 1) ? 1 : 0;
    if (i_w1 < 0) i_w1 = i_in + 1;
    if (i_w2 < 0) i_w2 = i_w1 + 1;

    const size_t need = (size_t)W1_ELEMS * sizeof(ushort);  // 512 KiB
    if (ws_size >= need) {
        ushort* w1s = (ushort*)d_ws;
        prep_kernel<<<dim3(W1_ELEMS / (256 * 8)), dim3(256), 0, stream>>>(
            d_in[i_in], d_in[i_w1], w1s);
        main_kernel<<<dim3(1024), dim3(256), 0, stream>>>(
            d_in[i_in], w1s, d_in[i_w2], d_out);
    } else {
        fallback_kernel<<<dim3(16 * 128), dim3(256), 0, stream>>>(
            d_in[i_in], d_in[i_w1], d_in[i_w2], d_out);
    }
}